// Round 11
// baseline (222.234 us; speedup 1.0000x reference)
//
#include <hip/hip_runtime.h>

using sh8 = __attribute__((ext_vector_type(8))) short;
using sh4 = __attribute__((ext_vector_type(4))) short;
using fx4 = __attribute__((ext_vector_type(4))) float;

#define MFMA(a,b,c)   __builtin_amdgcn_mfma_f32_16x16x32_bf16((a),(b),(c),0,0,0)

// RNE cast (epilogue scalars — accuracy-critical path)
__device__ __forceinline__ short f2bf(float f) {
    union { float f; unsigned u; } v; v.f = f;
    return (short)((v.u + 0x7fffu + ((v.u >> 16) & 1u)) >> 16);
}

// Single-instruction RNE pack of two floats to a bf16 pair (lo in low half).
__device__ __forceinline__ unsigned cvtpk(float lo, float hi) {
    unsigned r;
    asm("v_cvt_pk_bf16_f32 %0, %1, %2" : "=v"(r) : "v"(lo), "v"(hi));
    return r;
}

__device__ __forceinline__ sh8 pack8(float4 a, float4 b) {
    union { unsigned u[4]; sh8 s; } r;
    r.u[0] = cvtpk(a.x, a.y);
    r.u[1] = cvtpk(a.z, a.w);
    r.u[2] = cvtpk(b.x, b.y);
    r.u[3] = cvtpk(b.z, b.w);
    return r.s;
}

// q scale: D^-0.5 * log2(e) folded together; attn uses exp2 directly.
#define QSCALE 0.18033688011112042f

// DMA one 1KB chunk: per-lane global src, wave-uniform LDS dst (+lane*16 by HW)
#define GLOAD_LDS16(gsrc, ldst) __builtin_amdgcn_global_load_lds( \
    (const __attribute__((address_space(1))) void*)(gsrc),        \
    (__attribute__((address_space(3))) void*)(ldst), 16, 0, 0)

// ===========================================================================
// cast_k: one-shot fp32->bf16 of x (8192x768), Wq (768x768), Wkv (256x768)
// into the out-buffer's main region (dead until projgemm_k overwrites it).
// Wp is cast separately by wpcast_k into q_ws (dead after attn_k) — it must
// not alias out, which projgemm writes while reading it.
// ===========================================================================
__global__ __launch_bounds__(256) void cast_k(const float* __restrict__ x,
                                              const float* __restrict__ Wq,
                                              const float* __restrict__ Wkv,
                                              short* __restrict__ xbf,
                                              short* __restrict__ wqbf,
                                              short* __restrict__ wkvbf)
{
    const int blk = blockIdx.x, t = threadIdx.x;
    const float* src; short* dst; size_t idx8;
    if (blk < 3072)      { src = x;   dst = xbf;   idx8 = ((size_t)blk * 256 + t) * 8; }
    else if (blk < 3360) { src = Wq;  dst = wqbf;  idx8 = ((size_t)(blk - 3072) * 256 + t) * 8; }
    else                 { src = Wkv; dst = wkvbf; idx8 = ((size_t)(blk - 3360) * 256 + t) * 8; }
    float4 a = *(const float4*)(src + idx8);
    float4 b = *(const float4*)(src + idx8 + 4);
    *(sh8*)&dst[idx8] = pack8(a, b);
}

// wpcast_k: Wp (768x768 fp32) -> bf16 into q_ws region (dead after attn_k).
__global__ __launch_bounds__(256) void wpcast_k(const float* __restrict__ Wp,
                                                short* __restrict__ wpbf)
{
    const size_t idx8 = ((size_t)blockIdx.x * 256 + threadIdx.x) * 8;
    float4 a = *(const float4*)(Wp + idx8);
    float4 b = *(const float4*)(Wp + idx8 + 4);
    *(sh8*)&wpbf[idx8] = pack8(a, b);
}

// ===========================================================================
// Fragment layouts (k_ws / vT_ws, unchanged):
//   k_ws : per bh, 256 chunks of 512 shorts; group (kb,g) = 4 chunks.
//   vT_ws: per bh, 256 chunks; chunk (kb*2+g)*4+dt = V B-operand permutation.
//   Chunks are lane-linear (lane*16B) => global_load_lds-compatible.
// GEMM staging (prep/proj): fragment-order chunk DMA (R9, proven).
// ===========================================================================

// prep_k: merged qgemm+kvgemm (blocks 0..511, XCD-co-resident swizzle,
// ring-4 counted-vmcnt DMA pipeline) + depth_k cast (512..1535) +
// depth_v fragment gather (1536..2047).
__global__ __launch_bounds__(256) void prep_k(const short* __restrict__ xbf,
                                              const short* __restrict__ wqbf,
                                              const short* __restrict__ wkvbf,
                                              const float* __restrict__ bq,
                                              const float* __restrict__ bkv,
                                              const float* __restrict__ dk,
                                              const float* __restrict__ dv,
                                              float* __restrict__ ok,
                                              float* __restrict__ ov,
                                              short* __restrict__ q_ws,
                                              short* __restrict__ k_ws,
                                              short* __restrict__ vT_ws)
{
    __shared__ alignas(16) short L[4][16][512];   // 64 KB ring: 8 A + 8 B chunks
    const int blk = blockIdx.x;
    const int t   = threadIdx.x;

    if (blk < 512) {
        // ----- 128x128-tile bf16 GEMM (qgemm or kvgemm), DMA pipeline -----
        const int x8 = blk & 7, jj = blk >> 3;       // jj in [0,64)
        const int m  = x8 * 8 + (jj >> 3);           // [0,64)
        const int nn = jj & 7;                       // 0..5 q, 6..7 kv
        const bool isq = (nn < 6);
        const int  bm  = m * 128, bn = (isq ? nn : nn - 6) * 128;
        const short* Wmat = isq ? wqbf : wkvbf;

        const int wave = t >> 6, lane = t & 63;
        const int wm   = wave >> 1, wn = wave & 1;
        const int lhi  = lane >> 4, llo = lane & 15;
        const int l15  = lane & 15, l4 = lane >> 4;

        const short* aSrc0 = xbf  + (size_t)(bm + wave*16     + l15)*768 + l4*8;
        const short* aSrc1 = xbf  + (size_t)(bm + (wave+4)*16 + l15)*768 + l4*8;
        const short* bSrc0 = Wmat + (size_t)(bn + wave*16     + l15)*768 + l4*8;
        const short* bSrc1 = Wmat + (size_t)(bn + (wave+4)*16 + l15)*768 + l4*8;

        auto stage = [&](int s) {                     // k-step s: k0 = s*32
            const int r = s & 3;
            GLOAD_LDS16(aSrc0 + s*32, &L[r][wave][0]);
            GLOAD_LDS16(aSrc1 + s*32, &L[r][4 + wave][0]);
            GLOAD_LDS16(bSrc0 + s*32, &L[r][8 + wave][0]);
            GLOAD_LDS16(bSrc1 + s*32, &L[r][12 + wave][0]);
        };

        fx4 zero = {0.f, 0.f, 0.f, 0.f};
        fx4 acc[4][4];
        #pragma unroll
        for (int a = 0; a < 4; ++a)
            #pragma unroll
            for (int b2 = 0; b2 < 4; ++b2) acc[a][b2] = zero;

        stage(0);
        stage(1);                                     // 8 DMAs outstanding

        for (int s = 0; s < 24; ++s) {
            if (s < 22) {
                stage(s + 2);                         // outstanding 12
                asm volatile("s_waitcnt vmcnt(8)" ::: "memory");   // step s landed
            } else if (s == 22) {
                asm volatile("s_waitcnt vmcnt(4)" ::: "memory");
            } else {
                asm volatile("s_waitcnt vmcnt(0)" ::: "memory");
            }
            __builtin_amdgcn_s_barrier();
            __builtin_amdgcn_sched_barrier(0);

            const short* Lb = (const short*)&L[s & 3][0][0];
            const int lo = lane * 8;
            sh8 af[4], bf[4];
            #pragma unroll
            for (int mt = 0; mt < 4; ++mt)
                af[mt] = *(const sh8*)(Lb + (wm*4 + mt)*512 + lo);
            #pragma unroll
            for (int nt = 0; nt < 4; ++nt)
                bf[nt] = *(const sh8*)(Lb + (8 + wn*4 + nt)*512 + lo);
            #pragma unroll
            for (int mt = 0; mt < 4; ++mt)
                #pragma unroll
                for (int nt = 0; nt < 4; ++nt)
                    acc[mt][nt] = MFMA(af[mt], bf[nt], acc[mt][nt]);
        }

        if (isq) {
            #pragma unroll
            for (int nt = 0; nt < 4; ++nt) {
                const int c = bn + wn*64 + nt*16 + llo;
                const float bias = bq[c];
                const int g = c >> 7, h = (c >> 6) & 1, d = c & 63;
                #pragma unroll
                for (int mt = 0; mt < 4; ++mt) {
                    const int m0 = bm + wm*64 + mt*16 + lhi*4;
                    #pragma unroll
                    for (int r = 0; r < 4; ++r) {
                        const int mr = m0 + r;
                        const int b = mr >> 10, n = mr & 1023;
                        const float val = (acc[mt][nt][r] + bias) * QSCALE;
                        q_ws[((size_t)(b*2 + h)*6144 + n*6 + g)*64 + d] = f2bf(val);
                    }
                }
            }
        } else {
            #pragma unroll
            for (int nt = 0; nt < 4; ++nt) {
                const int c = bn + wn*64 + nt*16 + llo;     // 0..255
                const float bias = bkv[c];
                const int s = c >> 7, h = (c >> 6) & 1, d = c & 63;
                #pragma unroll
                for (int mt = 0; mt < 4; ++mt) {
                    const int m0 = bm + wm*64 + mt*16 + lhi*4;
                    const int b = m0 >> 10, n0 = m0 & 1023;
                    float vals[4];
                    #pragma unroll
                    for (int r = 0; r < 4; ++r) vals[r] = acc[mt][nt][r] + bias;
                    const int key = 1024 + n0;              // n0 % 4 == 0
                    if (s == 0) {
                        #pragma unroll
                        for (int r = 0; r < 4; ++r)
                            ok[((size_t)(b*1024 + n0 + r)*2 + h)*64 + d] = vals[r];
                        const int kb_ = key >> 6, nt_ = (key >> 4) & 3;
                        const int half = d >> 5, lhiK = (d >> 3) & 3, jK = d & 7;
                        const size_t base = (size_t)(b*2 + h)*131072
                            + (size_t)(((((kb_*4 + nt_)*2 + half)*64) + lhiK*16 + (key & 15))*8 + jK);
                        #pragma unroll
                        for (int r = 0; r < 4; ++r)
                            k_ws[base + r*8] = f2bf(vals[r]);
                    } else {
                        #pragma unroll
                        for (int r = 0; r < 4; ++r)
                            ov[((size_t)(b*1024 + n0 + r)*2 + h)*64 + d] = vals[r];
                        const int kb_ = key >> 6, g_ = (key >> 5) & 1, k5 = key & 31;
                        const int half5 = k5 >> 4, lhi5 = (k5 >> 2) & 3;   // j5 = r
                        const int dt_ = d >> 4, llov = d & 15;
                        short4 pk = make_short4(f2bf(vals[0]), f2bf(vals[1]),
                                                f2bf(vals[2]), f2bf(vals[3]));
                        const size_t base = (size_t)(b*2 + h)*131072
                            + (size_t)(((((kb_*2 + g_)*4 + dt_)*64) + lhi5*16 + llov)*8 + half5*4);
                        *(short4*)&vT_ws[base] = pk;
                    }
                }
            }
        }
    } else if (blk < 1536) {
        // ----- depth_k cast: [b][tt][h][d] fp32 -> k_ws fragment layout -----
        const size_t idx4 = ((size_t)(blk - 512) * 256 + t) * 4;
        const int b  = (int)(idx4 >> 17);
        const int rm = (int)(idx4 & 131071);
        const int tt = rm >> 7, h = (rm >> 6) & 1, d = rm & 63;   // d % 4 == 0
        float4 v = *(const float4*)(dk + idx4);
        short4 pk = make_short4(f2bf(v.x), f2bf(v.y), f2bf(v.z), f2bf(v.w));
        const int kb_ = tt >> 6, nt_ = (tt >> 4) & 3, lloK = tt & 15;
        const int half = d >> 5, lhiK = (d >> 3) & 3, jK = d & 7;  // jK in {0,4}
        const size_t addr = (size_t)(b*2 + h)*131072
            + (size_t)(((((kb_*4 + nt_)*2 + half)*64) + lhiK*16 + lloK)*8 + jK);
        *(short4*)&k_ws[addr] = pk;
    } else {
        // ----- depth_v: direct gather into V fragment layout -----
        const int unit = (blk - 1536)*4 + (t >> 6);   // 0..2047
        const int lane = t & 63, lhi = lane >> 4, llo = lane & 15;
        const int dt_ = unit & 3, g_ = (unit >> 2) & 1;
        const int kb_ = (unit >> 3) & 15, bh = unit >> 7;
        const int b = bh >> 1, h = bh & 1;
        const float* s0 = dv
            + ((size_t)((b*1024 + kb_*64 + g_*32 + lhi*4)*2 + h))*64 + dt_*16 + llo;
        union { short s[8]; sh8 v8; } o;
        #pragma unroll
        for (int jv = 0; jv < 4; ++jv) o.s[jv]     = f2bf(s0[(size_t)jv * 128]);
        #pragma unroll
        for (int jv = 0; jv < 4; ++jv) o.s[4 + jv] = f2bf(s0[(size_t)(16 + jv) * 128]);
        *(sh8*)&vT_ws[((size_t)bh*256 + (kb_*2 + g_)*4 + dt_)*512 + lane*8] = o.v8;
    }
}

// ---------------------------------------------------------------------------
// Attention v12: BARRIER-FREE per-wave pipelines.  Each wave DMAs its own
// 8 K/V chunks per 32-key group into a PRIVATE 16 KB LDS ring-2 region and
// syncs only on its own counted vmcnt(8) — zero s_barrier in the main loop.
// Waves on a SIMD free-run at different phases, so MFMA / exp2+pack / DMA
// overlap across waves instead of executing in barrier-lockstep sequence
// (R7 falsified wave-count as the limiter; this removes the coupling).
// Geometry: 512 blocks (= exactly 2/CU at 64 KB LDS), 192 q/block,
// 48 q/wave (3 subtiles) — R0-proven index math.  bh-co-location swizzle.
// s_setprio(1) around the PV MFMA cluster (T5: waves now phase-diverse).
// WAR safety without barriers: stage(g+1) overwrites slot (g-1)&1, whose
// ds_reads completed in program order (compiler lgkmcnt waits precede the
// consuming MFMAs of iteration g-1, which precede this stage issue).
// ---------------------------------------------------------------------------
__global__ __launch_bounds__(256) void attn_k(const short* __restrict__ q_ws,
                                              const short* __restrict__ k_ws,
                                              const short* __restrict__ vT_ws,
                                              short* __restrict__ o_ws)
{
    __shared__ alignas(16) short L[2][4][8][512];   // 64 KB [ring][wave][chunk]
    const int t    = threadIdx.x;
    const int wave = t >> 6, lane = t & 63;
    const int lhi  = lane >> 4, llo = lane & 15;
    const int blk  = blockIdx.x;
    const int x8   = blk & 7, jj = blk >> 3;       // jj in [0,64)
    const int bh   = x8 * 2 + (jj >= 32 ? 1 : 0);
    const int qt   = (jj >= 32) ? (jj - 32) : jj;  // [0,32)
    const int b    = bh >> 1, h = bh & 1;

    const short* qb = q_ws + ((size_t)bh*6144 + qt*192 + wave*48) * 64;
    sh8 qf[3][2];
    #pragma unroll
    for (int s = 0; s < 3; ++s) {
        qf[s][0] = *(const sh8*)(qb + (s*16 + llo)*64 + lhi*8);
        qf[s][1] = *(const sh8*)(qb + (s*16 + llo)*64 + lhi*8 + 32);
    }

    const short* kb_ = k_ws  + (size_t)bh*131072 + lane*8;
    const short* vb_ = vT_ws + (size_t)bh*131072 + lane*8;

    // Per-wave private stage: 8 chunks of group g into ring slot g&1.
    auto stage = [&](int g) {
        const short* ks = kb_ + (size_t)g * 2048;
        const short* vs = vb_ + (size_t)g * 2048;
        short* dst = &L[g & 1][wave][0][0];
        GLOAD_LDS16(ks,        dst);
        GLOAD_LDS16(ks + 512,  dst + 512);
        GLOAD_LDS16(ks + 1024, dst + 1024);
        GLOAD_LDS16(ks + 1536, dst + 1536);
        GLOAD_LDS16(vs,        dst + 2048);
        GLOAD_LDS16(vs + 512,  dst + 2560);
        GLOAD_LDS16(vs + 1024, dst + 3072);
        GLOAD_LDS16(vs + 1536, dst + 3584);
    };

    fx4 zero = {0.f, 0.f, 0.f, 0.f};
    fx4 oacc[3][4];
    fx4 lacc[3];
    #pragma unroll
    for (int s = 0; s < 3; ++s) {
        lacc[s] = zero;
        #pragma unroll
        for (int dt = 0; dt < 4; ++dt) oacc[s][dt] = zero;
    }

    union { unsigned u[4]; sh8 s8; } onesu;
    onesu.u[0] = onesu.u[1] = onesu.u[2] = onesu.u[3] = 0x3F803F80u;  // bf16 1.0 x8
    const sh8 ones = onesu.s8;

    stage(0);                                  // 8 outstanding

    for (int g = 0; g < 64; ++g) {
        if (g < 63) {
            stage(g + 1);                      // outstanding 16
            asm volatile("s_waitcnt vmcnt(8)" ::: "memory");   // group g landed
        } else {
            asm volatile("s_waitcnt vmcnt(0)" ::: "memory");
        }
        __builtin_amdgcn_sched_barrier(0);     // keep ds_reads below the wait

        const short* Lb = (const short*)&L[g & 1][wave][0][0];
        const int lo = lane * 8;
        sh8 K0 = *(const sh8*)(Lb + lo);
        sh8 K1 = *(const sh8*)(Lb + 512  + lo);
        sh8 K2 = *(const sh8*)(Lb + 1024 + lo);
        sh8 K3 = *(const sh8*)(Lb + 1536 + lo);
        sh8 V0 = *(const sh8*)(Lb + 2048 + lo);
        sh8 V1 = *(const sh8*)(Lb + 2560 + lo);
        sh8 V2 = *(const sh8*)(Lb + 3072 + lo);
        sh8 V3 = *(const sh8*)(Lb + 3584 + lo);

        #pragma unroll
        for (int s = 0; s < 3; ++s) {
            fx4 stA = MFMA(K0, qf[s][0], zero); stA = MFMA(K1, qf[s][1], stA);
            fx4 stB = MFMA(K2, qf[s][0], zero); stB = MFMA(K3, qf[s][1], stB);
            float pa0 = __builtin_amdgcn_exp2f(stA[0]);
            float pa1 = __builtin_amdgcn_exp2f(stA[1]);
            float pa2 = __builtin_amdgcn_exp2f(stA[2]);
            float pa3 = __builtin_amdgcn_exp2f(stA[3]);
            float pb0 = __builtin_amdgcn_exp2f(stB[0]);
            float pb1 = __builtin_amdgcn_exp2f(stB[1]);
            float pb2 = __builtin_amdgcn_exp2f(stB[2]);
            float pb3 = __builtin_amdgcn_exp2f(stB[3]);
            union { unsigned u[4]; sh8 s8; } pu;
            pu.u[0] = cvtpk(pa0, pa1);
            pu.u[1] = cvtpk(pa2, pa3);
            pu.u[2] = cvtpk(pb0, pb1);
            pu.u[3] = cvtpk(pb2, pb3);
            __builtin_amdgcn_s_setprio(1);
            lacc[s]    = MFMA(pu.s8, ones, lacc[s]);
            oacc[s][0] = MFMA(pu.s8, V0, oacc[s][0]);
            oacc[s][1] = MFMA(pu.s8, V1, oacc[s][1]);
            oacc[s][2] = MFMA(pu.s8, V2, oacc[s][2]);
            oacc[s][3] = MFMA(pu.s8, V3, oacc[s][3]);
            __builtin_amdgcn_s_setprio(0);
        }
    }

    // epilogue: lacc[s][r] holds the full denominator for q-row
    // s*16 + lhi*4 + r (identical across llo) — no shuffles needed.
    #pragma unroll
    for (int s = 0; s < 3; ++s) {
        #pragma unroll
        for (int r = 0; r < 4; ++r) {
            const float iq = 1.0f / lacc[s][r];
            const int qi = qt*192 + wave*48 + s*16 + lhi*4 + r;
            const int n = qi / 6, g6 = qi % 6;
            short* orow = o_ws + ((size_t)(b*1024 + n))*768 + g6*128 + h*64;
            #pragma unroll
            for (int dt = 0; dt < 4; ++dt)
                orow[dt*16 + llo] = f2bf(oacc[s][dt][r] * iq);
        }
    }
}

// ---------------------------------------------------------------------------
// proj GEMM: out = o(8192x768,bf16) @ Wp_bf^T + bproj -> fp32.  128x64 tiles,
// 768 blocks = 3/CU, XCD swizzle, ring-4 counted-vmcnt DMA pipeline (R9).
// wpbf lives in q_ws (dead after attn) — no aliasing with out.
// ---------------------------------------------------------------------------
__global__ __launch_bounds__(256) void projgemm_k(const short* __restrict__ o_ws,
                                                  const short* __restrict__ wpbf,
                                                  const float* __restrict__ bpj,
                                                  float* __restrict__ out)
{
    __shared__ alignas(16) short L[4][12][512];   // 48 KB ring: 8 A + 4 B chunks
    const int t    = threadIdx.x;
    const int wave = t >> 6, lane = t & 63;
    const int wm   = wave >> 1, wn = wave & 1;
    const int lhi  = lane >> 4, llo = lane & 15;
    const int l15  = lane & 15, l4 = lane >> 4;
    const int x8   = blockIdx.x & 7, jj = blockIdx.x >> 3;   // jj in [0,96)
    const int bm   = (x8*8 + jj/12) * 128;
    const int bn   = (jj % 12) * 64;

    const short* aSrc0 = o_ws + (size_t)(bm + wave*16     + l15)*768 + l4*8;
    const short* aSrc1 = o_ws + (size_t)(bm + (wave+4)*16 + l15)*768 + l4*8;
    const short* bSrc  = wpbf + (size_t)(bn + wave*16     + l15)*768 + l4*8;

    auto stage = [&](int s) {
        const int r = s & 3;
        GLOAD_LDS16(aSrc0 + s*32, &L[r][wave][0]);
        GLOAD_LDS16(aSrc1 + s*32, &L[r][4 + wave][0]);
        GLOAD_LDS16(bSrc  + s*32, &L[r][8 + wave][0]);
    };

    fx4 zero = {0.f, 0.f, 0.f, 0.f};
    fx4 acc[4][2];
    #pragma unroll
    for (int i = 0; i < 4; ++i)
        #pragma unroll
        for (int j2 = 0; j2 < 2; ++j2) acc[i][j2] = zero;

    stage(0);
    stage(1);                                     // 6 DMAs outstanding

    for (int s = 0; s < 24; ++s) {
        if (s < 22) {
            stage(s + 2);                         // outstanding 9
            asm volatile("s_waitcnt vmcnt(6)" ::: "memory");   // step s landed
        } else if (s == 22) {
            asm volatile("s_waitcnt vmcnt(3)" ::: "memory");
        } else {
            asm volatile("s_waitcnt vmcnt(0)" ::: "memory");
        }
        __builtin_amdgcn_s_barrier();
        __builtin_amdgcn_sched_barrier(0);

        const short* Lb = (const short*)&L[s & 3][0][0];
        const int lo = lane * 8;
        sh8 af[4], bf[2];
        #pragma unroll
        for (int mt = 0; mt < 4; ++mt)
            af[mt] = *(const sh8*)(Lb + (wm*4 + mt)*512 + lo);
        #pragma unroll
        for (int nt = 0; nt < 2; ++nt)
            bf[nt] = *(const sh8*)(Lb + (8 + wn*2 + nt)*512 + lo);
        #pragma unroll
        for (int mt = 0; mt < 4; ++mt)
            #pragma unroll
            for (int nt = 0; nt < 2; ++nt)
                acc[mt][nt] = MFMA(af[mt], bf[nt], acc[mt][nt]);
    }

    #pragma unroll
    for (int nt = 0; nt < 2; ++nt) {
        const int c = bn + wn*32 + nt*16 + llo;
        const float bias = bpj[c];
        #pragma unroll
        for (int mt = 0; mt < 4; ++mt) {
            const int m0 = bm + wm*64 + mt*16 + lhi*4;
            #pragma unroll
            for (int r = 0; r < 4; ++r)
                out[(size_t)(m0 + r)*768 + c] = acc[mt][nt][r] + bias;
        }
    }
}

// ---------------------------------------------------------------------------
extern "C" void kernel_launch(void* const* d_in, const int* in_sizes, int n_in,
                              void* d_out, int out_size, void* d_ws, size_t ws_size,
                              hipStream_t stream)
{
    const float* x   = (const float*)d_in[0];
    const float* dk  = (const float*)d_in[1];
    const float* dv  = (const float*)d_in[2];
    const float* Wq  = (const float*)d_in[3];
    const float* bq  = (const float*)d_in[4];
    const float* Wkv = (const float*)d_in[5];
    const float* bkv = (const float*)d_in[6];
    const float* Wp  = (const float*)d_in[7];
    const float* bpj = (const float*)d_in[8];

    float* out = (float*)d_out;
    float* ok  = out + 6291456;            // k output (8,1024,2,64)
    float* ov  = out + 7340032;            // v output

    // bf16 scratch inside the out-buffer's main region (dead until projgemm
    // overwrites it; none of it is read by projgemm):
    short* xbf   = (short*)out;
    short* wqbf  = xbf + 6291456;
    short* wkvbf = wqbf + 589824;

    char* ws = (char*)d_ws;
    short* q_ws  = (short*)(ws);                    // 12,582,912 B
    short* k_ws  = (short*)(ws + 12582912);         //  4,194,304 B (frag layout)
    short* vT_ws = (short*)(ws + 16777216);         //  4,194,304 B (frag layout)
    short* o_ws  = (short*)(ws + 20971520);         // 12,582,912 B  (32 MiB total)

    short* wpbf  = q_ws;                   // q_ws region is dead after attn_k

    cast_k     <<<dim3(3456), 256, 0, stream>>>(x, Wq, Wkv, xbf, wqbf, wkvbf);
    prep_k     <<<dim3(2048), 256, 0, stream>>>(xbf, wqbf, wkvbf, bq, bkv, dk, dv,
                                                ok, ov, q_ws, k_ws, vT_ws);
    attn_k     <<<dim3(512),  256, 0, stream>>>(q_ws, k_ws, vT_ws, o_ws);
    wpcast_k   <<<dim3(288),  256, 0, stream>>>(Wp, wpbf);
    projgemm_k <<<dim3(768),  256, 0, stream>>>(o_ws, wpbf, bpj, out);
}

// Round 12
// 215.975 us; speedup vs baseline: 1.0290x; 1.0290x over previous
//
#include <hip/hip_runtime.h>

using sh8 = __attribute__((ext_vector_type(8))) short;
using sh4 = __attribute__((ext_vector_type(4))) short;
using fx4 = __attribute__((ext_vector_type(4))) float;

#define MFMA(a,b,c)   __builtin_amdgcn_mfma_f32_16x16x32_bf16((a),(b),(c),0,0,0)

// RNE cast (epilogue scalars — accuracy-critical path)
__device__ __forceinline__ short f2bf(float f) {
    union { float f; unsigned u; } v; v.f = f;
    return (short)((v.u + 0x7fffu + ((v.u >> 16) & 1u)) >> 16);
}

// Single-instruction RNE pack of two floats to a bf16 pair (lo in low half).
__device__ __forceinline__ unsigned cvtpk(float lo, float hi) {
    unsigned r;
    asm("v_cvt_pk_bf16_f32 %0, %1, %2" : "=v"(r) : "v"(lo), "v"(hi));
    return r;
}

__device__ __forceinline__ sh8 pack8(float4 a, float4 b) {
    union { unsigned u[4]; sh8 s; } r;
    r.u[0] = cvtpk(a.x, a.y);
    r.u[1] = cvtpk(a.z, a.w);
    r.u[2] = cvtpk(b.x, b.y);
    r.u[3] = cvtpk(b.z, b.w);
    return r.s;
}

// q scale: D^-0.5 * log2(e) folded together; attn uses exp2 directly.
#define QSCALE 0.18033688011112042f

// DMA one 1KB chunk: per-lane global src, wave-uniform LDS dst (+lane*16 by HW)
#define GLOAD_LDS16(gsrc, ldst) __builtin_amdgcn_global_load_lds( \
    (const __attribute__((address_space(1))) void*)(gsrc),        \
    (__attribute__((address_space(3))) void*)(ldst), 16, 0, 0)

// ===========================================================================
// cast_k: one-shot fp32->bf16 of x (8192x768), Wq (768x768), Wkv (256x768)
// into the out-buffer's main region (dead until projgemm_k overwrites it).
// Wp is cast separately by wpcast_k into q_ws (dead after attn_k).
// ===========================================================================
__global__ __launch_bounds__(256) void cast_k(const float* __restrict__ x,
                                              const float* __restrict__ Wq,
                                              const float* __restrict__ Wkv,
                                              short* __restrict__ xbf,
                                              short* __restrict__ wqbf,
                                              short* __restrict__ wkvbf)
{
    const int blk = blockIdx.x, t = threadIdx.x;
    const float* src; short* dst; size_t idx8;
    if (blk < 3072)      { src = x;   dst = xbf;   idx8 = ((size_t)blk * 256 + t) * 8; }
    else if (blk < 3360) { src = Wq;  dst = wqbf;  idx8 = ((size_t)(blk - 3072) * 256 + t) * 8; }
    else                 { src = Wkv; dst = wkvbf; idx8 = ((size_t)(blk - 3360) * 256 + t) * 8; }
    float4 a = *(const float4*)(src + idx8);
    float4 b = *(const float4*)(src + idx8 + 4);
    *(sh8*)&dst[idx8] = pack8(a, b);
}

// wpcast_k: Wp (768x768 fp32) -> bf16 into q_ws region (dead after attn_k).
__global__ __launch_bounds__(256) void wpcast_k(const float* __restrict__ Wp,
                                                short* __restrict__ wpbf)
{
    const size_t idx8 = ((size_t)blockIdx.x * 256 + threadIdx.x) * 8;
    float4 a = *(const float4*)(Wp + idx8);
    float4 b = *(const float4*)(Wp + idx8 + 4);
    *(sh8*)&wpbf[idx8] = pack8(a, b);
}

// ===========================================================================
// Fragment layouts (k_ws / vT_ws, unchanged):
//   k_ws : per bh, 256 chunks of 512 shorts; group (kb,g) = 4 chunks.
//   vT_ws: per bh, 256 chunks; chunk (kb*2+g)*4+dt = V B-operand permutation.
//   Chunks are lane-linear (lane*16B) => global_load_lds-compatible.
// GEMM staging (prep/proj): fragment-order chunk DMA (R9, proven).
// ===========================================================================

// prep_k: merged qgemm+kvgemm (blocks 0..511, XCD-co-resident swizzle,
// ring-4 counted-vmcnt DMA pipeline) + depth_k cast (512..1535) +
// depth_v fragment gather (1536..2047).
__global__ __launch_bounds__(256) void prep_k(const short* __restrict__ xbf,
                                              const short* __restrict__ wqbf,
                                              const short* __restrict__ wkvbf,
                                              const float* __restrict__ bq,
                                              const float* __restrict__ bkv,
                                              const float* __restrict__ dk,
                                              const float* __restrict__ dv,
                                              float* __restrict__ ok,
                                              float* __restrict__ ov,
                                              short* __restrict__ q_ws,
                                              short* __restrict__ k_ws,
                                              short* __restrict__ vT_ws)
{
    __shared__ alignas(16) short L[4][16][512];   // 64 KB ring: 8 A + 8 B chunks
    const int blk = blockIdx.x;
    const int t   = threadIdx.x;

    if (blk < 512) {
        // ----- 128x128-tile bf16 GEMM (qgemm or kvgemm), DMA pipeline -----
        const int x8 = blk & 7, jj = blk >> 3;       // jj in [0,64)
        const int m  = x8 * 8 + (jj >> 3);           // [0,64)
        const int nn = jj & 7;                       // 0..5 q, 6..7 kv
        const bool isq = (nn < 6);
        const int  bm  = m * 128, bn = (isq ? nn : nn - 6) * 128;
        const short* Wmat = isq ? wqbf : wkvbf;

        const int wave = t >> 6, lane = t & 63;
        const int wm   = wave >> 1, wn = wave & 1;
        const int lhi  = lane >> 4, llo = lane & 15;
        const int l15  = lane & 15, l4 = lane >> 4;

        const short* aSrc0 = xbf  + (size_t)(bm + wave*16     + l15)*768 + l4*8;
        const short* aSrc1 = xbf  + (size_t)(bm + (wave+4)*16 + l15)*768 + l4*8;
        const short* bSrc0 = Wmat + (size_t)(bn + wave*16     + l15)*768 + l4*8;
        const short* bSrc1 = Wmat + (size_t)(bn + (wave+4)*16 + l15)*768 + l4*8;

        auto stage = [&](int s) {                     // k-step s: k0 = s*32
            const int r = s & 3;
            GLOAD_LDS16(aSrc0 + s*32, &L[r][wave][0]);
            GLOAD_LDS16(aSrc1 + s*32, &L[r][4 + wave][0]);
            GLOAD_LDS16(bSrc0 + s*32, &L[r][8 + wave][0]);
            GLOAD_LDS16(bSrc1 + s*32, &L[r][12 + wave][0]);
        };

        fx4 zero = {0.f, 0.f, 0.f, 0.f};
        fx4 acc[4][4];
        #pragma unroll
        for (int a = 0; a < 4; ++a)
            #pragma unroll
            for (int b2 = 0; b2 < 4; ++b2) acc[a][b2] = zero;

        stage(0);
        stage(1);                                     // 8 DMAs outstanding

        for (int s = 0; s < 24; ++s) {
            if (s < 22) {
                stage(s + 2);                         // outstanding 12
                asm volatile("s_waitcnt vmcnt(8)" ::: "memory");   // step s landed
            } else if (s == 22) {
                asm volatile("s_waitcnt vmcnt(4)" ::: "memory");
            } else {
                asm volatile("s_waitcnt vmcnt(0)" ::: "memory");
            }
            __builtin_amdgcn_s_barrier();
            __builtin_amdgcn_sched_barrier(0);

            const short* Lb = (const short*)&L[s & 3][0][0];
            const int lo = lane * 8;
            sh8 af[4], bf[4];
            #pragma unroll
            for (int mt = 0; mt < 4; ++mt)
                af[mt] = *(const sh8*)(Lb + (wm*4 + mt)*512 + lo);
            #pragma unroll
            for (int nt = 0; nt < 4; ++nt)
                bf[nt] = *(const sh8*)(Lb + (8 + wn*4 + nt)*512 + lo);
            #pragma unroll
            for (int mt = 0; mt < 4; ++mt)
                #pragma unroll
                for (int nt = 0; nt < 4; ++nt)
                    acc[mt][nt] = MFMA(af[mt], bf[nt], acc[mt][nt]);
        }

        if (isq) {
            #pragma unroll
            for (int nt = 0; nt < 4; ++nt) {
                const int c = bn + wn*64 + nt*16 + llo;
                const float bias = bq[c];
                const int g = c >> 7, h = (c >> 6) & 1, d = c & 63;
                #pragma unroll
                for (int mt = 0; mt < 4; ++mt) {
                    const int m0 = bm + wm*64 + mt*16 + lhi*4;
                    #pragma unroll
                    for (int r = 0; r < 4; ++r) {
                        const int mr = m0 + r;
                        const int b = mr >> 10, n = mr & 1023;
                        const float val = (acc[mt][nt][r] + bias) * QSCALE;
                        q_ws[((size_t)(b*2 + h)*6144 + n*6 + g)*64 + d] = f2bf(val);
                    }
                }
            }
        } else {
            #pragma unroll
            for (int nt = 0; nt < 4; ++nt) {
                const int c = bn + wn*64 + nt*16 + llo;     // 0..255
                const float bias = bkv[c];
                const int s = c >> 7, h = (c >> 6) & 1, d = c & 63;
                #pragma unroll
                for (int mt = 0; mt < 4; ++mt) {
                    const int m0 = bm + wm*64 + mt*16 + lhi*4;
                    const int b = m0 >> 10, n0 = m0 & 1023;
                    float vals[4];
                    #pragma unroll
                    for (int r = 0; r < 4; ++r) vals[r] = acc[mt][nt][r] + bias;
                    const int key = 1024 + n0;              // n0 % 4 == 0
                    if (s == 0) {
                        #pragma unroll
                        for (int r = 0; r < 4; ++r)
                            ok[((size_t)(b*1024 + n0 + r)*2 + h)*64 + d] = vals[r];
                        const int kb_ = key >> 6, nt_ = (key >> 4) & 3;
                        const int half = d >> 5, lhiK = (d >> 3) & 3, jK = d & 7;
                        const size_t base = (size_t)(b*2 + h)*131072
                            + (size_t)(((((kb_*4 + nt_)*2 + half)*64) + lhiK*16 + (key & 15))*8 + jK);
                        #pragma unroll
                        for (int r = 0; r < 4; ++r)
                            k_ws[base + r*8] = f2bf(vals[r]);
                    } else {
                        #pragma unroll
                        for (int r = 0; r < 4; ++r)
                            ov[((size_t)(b*1024 + n0 + r)*2 + h)*64 + d] = vals[r];
                        const int kb_ = key >> 6, g_ = (key >> 5) & 1, k5 = key & 31;
                        const int half5 = k5 >> 4, lhi5 = (k5 >> 2) & 3;   // j5 = r
                        const int dt_ = d >> 4, llov = d & 15;
                        short4 pk = make_short4(f2bf(vals[0]), f2bf(vals[1]),
                                                f2bf(vals[2]), f2bf(vals[3]));
                        const size_t base = (size_t)(b*2 + h)*131072
                            + (size_t)(((((kb_*2 + g_)*4 + dt_)*64) + lhi5*16 + llov)*8 + half5*4);
                        *(short4*)&vT_ws[base] = pk;
                    }
                }
            }
        }
    } else if (blk < 1536) {
        // ----- depth_k cast: [b][tt][h][d] fp32 -> k_ws fragment layout -----
        const size_t idx4 = ((size_t)(blk - 512) * 256 + t) * 4;
        const int b  = (int)(idx4 >> 17);
        const int rm = (int)(idx4 & 131071);
        const int tt = rm >> 7, h = (rm >> 6) & 1, d = rm & 63;   // d % 4 == 0
        float4 v = *(const float4*)(dk + idx4);
        short4 pk = make_short4(f2bf(v.x), f2bf(v.y), f2bf(v.z), f2bf(v.w));
        const int kb_ = tt >> 6, nt_ = (tt >> 4) & 3, lloK = tt & 15;
        const int half = d >> 5, lhiK = (d >> 3) & 3, jK = d & 7;  // jK in {0,4}
        const size_t addr = (size_t)(b*2 + h)*131072
            + (size_t)(((((kb_*4 + nt_)*2 + half)*64) + lhiK*16 + lloK)*8 + jK);
        *(short4*)&k_ws[addr] = pk;
    } else {
        // ----- depth_v: direct gather into V fragment layout -----
        const int unit = (blk - 1536)*4 + (t >> 6);   // 0..2047
        const int lane = t & 63, lhi = lane >> 4, llo = lane & 15;
        const int dt_ = unit & 3, g_ = (unit >> 2) & 1;
        const int kb_ = (unit >> 3) & 15, bh = unit >> 7;
        const int b = bh >> 1, h = bh & 1;
        const float* s0 = dv
            + ((size_t)((b*1024 + kb_*64 + g_*32 + lhi*4)*2 + h))*64 + dt_*16 + llo;
        union { short s[8]; sh8 v8; } o;
        #pragma unroll
        for (int jv = 0; jv < 4; ++jv) o.s[jv]     = f2bf(s0[(size_t)jv * 128]);
        #pragma unroll
        for (int jv = 0; jv < 4; ++jv) o.s[4 + jv] = f2bf(s0[(size_t)(16 + jv) * 128]);
        *(sh8*)&vT_ws[((size_t)bh*256 + (kb_*2 + g_)*4 + dt_)*512 + lane*8] = o.v8;
    }
}

// ---------------------------------------------------------------------------
// Attention v13: R5/R9-proven shared-staging schedule (256 thr, 32 q/wave,
// ring-4, counted vmcnt, bh-co-location swizzle) + 1-group SOFTWARE PIPELINE:
// iteration g runs {exp2/pack of group g} and {QK-MFMA of group g+1} in the
// SAME barrier window — independent bursts the scheduler can co-issue on the
// trans/VALU and MFMA pipes within one wave (T15 analog; R7/R11 falsified
// cross-wave occupancy and barrier-free as levers, this targets within-wave
// serialization).  Carried regs: S^T (16) + V (16) for the in-flight group.
// ---------------------------------------------------------------------------
__global__ __launch_bounds__(256) void attn_k(const short* __restrict__ q_ws,
                                              const short* __restrict__ k_ws,
                                              const short* __restrict__ vT_ws,
                                              short* __restrict__ o_ws)
{
    __shared__ alignas(16) short L[4][8][512];   // ring buf: 4 x (4 K + 4 V chunks)
    const int t    = threadIdx.x;
    const int wave = t >> 6, lane = t & 63;
    const int lhi  = lane >> 4, llo = lane & 15;
    const int blk  = blockIdx.x;
    const int x8   = blk & 7, jj = blk >> 3;       // jj in [0,96)
    const int bh   = x8 * 2 + (jj >= 48 ? 1 : 0);
    const int qt   = (jj >= 48) ? (jj - 48) : jj;  // [0,48)
    const int b    = bh >> 1, h = bh & 1;

    const short* qb = q_ws + ((size_t)bh*6144 + qt*128 + wave*32) * 64;
    sh8 qf[2][2];
    #pragma unroll
    for (int s = 0; s < 2; ++s) {
        qf[s][0] = *(const sh8*)(qb + (s*16 + llo)*64 + lhi*8);
        qf[s][1] = *(const sh8*)(qb + (s*16 + llo)*64 + lhi*8 + 32);
    }

    const short* kbase = k_ws  + (size_t)bh*131072;
    const short* vbase = vT_ws + (size_t)bh*131072;

    fx4 zero = {0.f, 0.f, 0.f, 0.f};
    fx4 oacc[2][4];
    fx4 lacc[2];
    #pragma unroll
    for (int s = 0; s < 2; ++s) {
        lacc[s] = zero;
        #pragma unroll
        for (int dt = 0; dt < 4; ++dt) oacc[s][dt] = zero;
    }

    union { unsigned u[4]; sh8 s8; } onesu;
    onesu.u[0] = onesu.u[1] = onesu.u[2] = onesu.u[3] = 0x3F803F80u;  // bf16 1.0 x8
    const sh8 ones = onesu.s8;

    auto stage = [&](int g) {
        const short* ks = kbase + ((size_t)g*4 + wave)*512 + lane*8;
        const short* vs = vbase + ((size_t)g*4 + wave)*512 + lane*8;
        GLOAD_LDS16(ks, &L[g & 3][wave][0]);
        GLOAD_LDS16(vs, &L[g & 3][4 + wave][0]);
    };

    const int lo = lane * 8;
    fx4 stc[2][2];          // carried S^T of the in-flight group [s][A/B]
    sh8 V0, V1, V2, V3;     // carried V fragments of the in-flight group

    // ---- prologue: stage 0..2, wait group 0, QK[0] ----
    stage(0);
    stage(1);
    stage(2);                                  // 6 outstanding
    asm volatile("s_waitcnt vmcnt(4)" ::: "memory");   // group 0 landed
    __builtin_amdgcn_s_barrier();
    __builtin_amdgcn_sched_barrier(0);
    {
        const short* Lb = (const short*)&L[0][0][0];
        sh8 K0 = *(const sh8*)(Lb + lo);
        sh8 K1 = *(const sh8*)(Lb + 512  + lo);
        sh8 K2 = *(const sh8*)(Lb + 1024 + lo);
        sh8 K3 = *(const sh8*)(Lb + 1536 + lo);
        V0 = *(const sh8*)(Lb + 2048 + lo);
        V1 = *(const sh8*)(Lb + 2560 + lo);
        V2 = *(const sh8*)(Lb + 3072 + lo);
        V3 = *(const sh8*)(Lb + 3584 + lo);
        #pragma unroll
        for (int s = 0; s < 2; ++s) {
            stc[s][0] = MFMA(K0, qf[s][0], zero); stc[s][0] = MFMA(K1, qf[s][1], stc[s][0]);
            stc[s][1] = MFMA(K2, qf[s][0], zero); stc[s][1] = MFMA(K3, qf[s][1], stc[s][1]);
        }
    }

    // ---- main loop: PV[g] + QK[g+1] per barrier window ----
    for (int g = 0; g < 63; ++g) {
        if (g < 61) {
            stage(g + 3);                      // outstanding 6
            asm volatile("s_waitcnt vmcnt(4)" ::: "memory");   // group g+1 landed
        } else if (g == 61) {
            asm volatile("s_waitcnt vmcnt(2)" ::: "memory");
        } else {
            asm volatile("s_waitcnt vmcnt(0)" ::: "memory");
        }
        __builtin_amdgcn_s_barrier();
        __builtin_amdgcn_sched_barrier(0);

        // issue next-group LDS reads early (latency covered by exp2 burst)
        const short* Lb = (const short*)&L[(g + 1) & 3][0][0];
        sh8 K0 = *(const sh8*)(Lb + lo);
        sh8 K1 = *(const sh8*)(Lb + 512  + lo);
        sh8 K2 = *(const sh8*)(Lb + 1024 + lo);
        sh8 K3 = *(const sh8*)(Lb + 1536 + lo);
        sh8 Vn0 = *(const sh8*)(Lb + 2048 + lo);
        sh8 Vn1 = *(const sh8*)(Lb + 2560 + lo);
        sh8 Vn2 = *(const sh8*)(Lb + 3072 + lo);
        sh8 Vn3 = *(const sh8*)(Lb + 3584 + lo);

        // exp2/pack for group g (register-only — independent of the reads)
        union { unsigned u[4]; sh8 s8; } pu[2];
        #pragma unroll
        for (int s = 0; s < 2; ++s) {
            float pa0 = __builtin_amdgcn_exp2f(stc[s][0][0]);
            float pa1 = __builtin_amdgcn_exp2f(stc[s][0][1]);
            float pa2 = __builtin_amdgcn_exp2f(stc[s][0][2]);
            float pa3 = __builtin_amdgcn_exp2f(stc[s][0][3]);
            float pb0 = __builtin_amdgcn_exp2f(stc[s][1][0]);
            float pb1 = __builtin_amdgcn_exp2f(stc[s][1][1]);
            float pb2 = __builtin_amdgcn_exp2f(stc[s][1][2]);
            float pb3 = __builtin_amdgcn_exp2f(stc[s][1][3]);
            pu[s].u[0] = cvtpk(pa0, pa1);
            pu[s].u[1] = cvtpk(pa2, pa3);
            pu[s].u[2] = cvtpk(pb0, pb1);
            pu[s].u[3] = cvtpk(pb2, pb3);
        }

        // QK-MFMA for group g+1 (consumes the ds_reads; independent of PV)
        fx4 stn[2][2];
        #pragma unroll
        for (int s = 0; s < 2; ++s) {
            stn[s][0] = MFMA(K0, qf[s][0], zero); stn[s][0] = MFMA(K1, qf[s][1], stn[s][0]);
            stn[s][1] = MFMA(K2, qf[s][0], zero); stn[s][1] = MFMA(K3, qf[s][1], stn[s][1]);
        }

        // PV-MFMA for group g (consumes pu and carried V)
        #pragma unroll
        for (int s = 0; s < 2; ++s) {
            lacc[s]    = MFMA(pu[s].s8, ones, lacc[s]);
            oacc[s][0] = MFMA(pu[s].s8, V0, oacc[s][0]);
            oacc[s][1] = MFMA(pu[s].s8, V1, oacc[s][1]);
            oacc[s][2] = MFMA(pu[s].s8, V2, oacc[s][2]);
            oacc[s][3] = MFMA(pu[s].s8, V3, oacc[s][3]);
        }

        // rotate carried state
        #pragma unroll
        for (int s = 0; s < 2; ++s) { stc[s][0] = stn[s][0]; stc[s][1] = stn[s][1]; }
        V0 = Vn0; V1 = Vn1; V2 = Vn2; V3 = Vn3;
    }

    // ---- drain: exp2 + PV for the final group (63) ----
    {
        union { unsigned u[4]; sh8 s8; } pu[2];
        #pragma unroll
        for (int s = 0; s < 2; ++s) {
            float pa0 = __builtin_amdgcn_exp2f(stc[s][0][0]);
            float pa1 = __builtin_amdgcn_exp2f(stc[s][0][1]);
            float pa2 = __builtin_amdgcn_exp2f(stc[s][0][2]);
            float pa3 = __builtin_amdgcn_exp2f(stc[s][0][3]);
            float pb0 = __builtin_amdgcn_exp2f(stc[s][1][0]);
            float pb1 = __builtin_amdgcn_exp2f(stc[s][1][1]);
            float pb2 = __builtin_amdgcn_exp2f(stc[s][1][2]);
            float pb3 = __builtin_amdgcn_exp2f(stc[s][1][3]);
            pu[s].u[0] = cvtpk(pa0, pa1);
            pu[s].u[1] = cvtpk(pa2, pa3);
            pu[s].u[2] = cvtpk(pb0, pb1);
            pu[s].u[3] = cvtpk(pb2, pb3);
        }
        #pragma unroll
        for (int s = 0; s < 2; ++s) {
            lacc[s]    = MFMA(pu[s].s8, ones, lacc[s]);
            oacc[s][0] = MFMA(pu[s].s8, V0, oacc[s][0]);
            oacc[s][1] = MFMA(pu[s].s8, V1, oacc[s][1]);
            oacc[s][2] = MFMA(pu[s].s8, V2, oacc[s][2]);
            oacc[s][3] = MFMA(pu[s].s8, V3, oacc[s][3]);
        }
    }

    // epilogue: lacc[s][r] holds the full denominator for q-row
    // s*16 + lhi*4 + r (identical across llo) — no shuffles needed.
    #pragma unroll
    for (int s = 0; s < 2; ++s) {
        #pragma unroll
        for (int r = 0; r < 4; ++r) {
            const float iq = 1.0f / lacc[s][r];
            const int qi = qt*128 + wave*32 + s*16 + lhi*4 + r;
            const int n = qi / 6, g6 = qi % 6;
            short* orow = o_ws + ((size_t)(b*1024 + n))*768 + g6*128 + h*64;
            #pragma unroll
            for (int dt = 0; dt < 4; ++dt)
                orow[dt*16 + llo] = f2bf(oacc[s][dt][r] * iq);
        }
    }
}

// ---------------------------------------------------------------------------
// proj GEMM: out = o(8192x768,bf16) @ Wp_bf^T + bproj -> fp32.  128x64 tiles,
// 768 blocks = 3/CU, XCD swizzle, ring-4 counted-vmcnt DMA pipeline (R9).
// wpbf lives in q_ws (dead after attn) — no aliasing with out.
// ---------------------------------------------------------------------------
__global__ __launch_bounds__(256) void projgemm_k(const short* __restrict__ o_ws,
                                                  const short* __restrict__ wpbf,
                                                  const float* __restrict__ bpj,
                                                  float* __restrict__ out)
{
    __shared__ alignas(16) short L[4][12][512];   // 48 KB ring: 8 A + 4 B chunks
    const int t    = threadIdx.x;
    const int wave = t >> 6, lane = t & 63;
    const int wm   = wave >> 1, wn = wave & 1;
    const int lhi  = lane >> 4, llo = lane & 15;
    const int l15  = lane & 15, l4 = lane >> 4;
    const int x8   = blockIdx.x & 7, jj = blockIdx.x >> 3;   // jj in [0,96)
    const int bm   = (x8*8 + jj/12) * 128;
    const int bn   = (jj % 12) * 64;

    const short* aSrc0 = o_ws + (size_t)(bm + wave*16     + l15)*768 + l4*8;
    const short* aSrc1 = o_ws + (size_t)(bm + (wave+4)*16 + l15)*768 + l4*8;
    const short* bSrc  = wpbf + (size_t)(bn + wave*16     + l15)*768 + l4*8;

    auto stage = [&](int s) {
        const int r = s & 3;
        GLOAD_LDS16(aSrc0 + s*32, &L[r][wave][0]);
        GLOAD_LDS16(aSrc1 + s*32, &L[r][4 + wave][0]);
        GLOAD_LDS16(bSrc  + s*32, &L[r][8 + wave][0]);
    };

    fx4 zero = {0.f, 0.f, 0.f, 0.f};
    fx4 acc[4][2];
    #pragma unroll
    for (int i = 0; i < 4; ++i)
        #pragma unroll
        for (int j2 = 0; j2 < 2; ++j2) acc[i][j2] = zero;

    stage(0);
    stage(1);                                     // 6 DMAs outstanding

    for (int s = 0; s < 24; ++s) {
        if (s < 22) {
            stage(s + 2);                         // outstanding 9
            asm volatile("s_waitcnt vmcnt(6)" ::: "memory");   // step s landed
        } else if (s == 22) {
            asm volatile("s_waitcnt vmcnt(3)" ::: "memory");
        } else {
            asm volatile("s_waitcnt vmcnt(0)" ::: "memory");
        }
        __builtin_amdgcn_s_barrier();
        __builtin_amdgcn_sched_barrier(0);

        const short* Lb = (const short*)&L[s & 3][0][0];
        const int lo = lane * 8;
        sh8 af[4], bf[2];
        #pragma unroll
        for (int mt = 0; mt < 4; ++mt)
            af[mt] = *(const sh8*)(Lb + (wm*4 + mt)*512 + lo);
        #pragma unroll
        for (int nt = 0; nt < 2; ++nt)
            bf[nt] = *(const sh8*)(Lb + (8 + wn*2 + nt)*512 + lo);
        #pragma unroll
        for (int mt = 0; mt < 4; ++mt)
            #pragma unroll
            for (int nt = 0; nt < 2; ++nt)
                acc[mt][nt] = MFMA(af[mt], bf[nt], acc[mt][nt]);
    }

    #pragma unroll
    for (int nt = 0; nt < 2; ++nt) {
        const int c = bn + wn*32 + nt*16 + llo;
        const float bias = bpj[c];
        #pragma unroll
        for (int mt = 0; mt < 4; ++mt) {
            const int m0 = bm + wm*64 + mt*16 + lhi*4;
            #pragma unroll
            for (int r = 0; r < 4; ++r)
                out[(size_t)(m0 + r)*768 + c] = acc[mt][nt][r] + bias;
        }
    }
}

// ---------------------------------------------------------------------------
extern "C" void kernel_launch(void* const* d_in, const int* in_sizes, int n_in,
                              void* d_out, int out_size, void* d_ws, size_t ws_size,
                              hipStream_t stream)
{
    const float* x   = (const float*)d_in[0];
    const float* dk  = (const float*)d_in[1];
    const float* dv  = (const float*)d_in[2];
    const float* Wq  = (const float*)d_in[3];
    const float* bq  = (const float*)d_in[4];
    const float* Wkv = (const float*)d_in[5];
    const float* bkv = (const float*)d_in[6];
    const float* Wp  = (const float*)d_in[7];
    const float* bpj = (const float*)d_in[8];

    float* out = (float*)d_out;
    float* ok  = out + 6291456;            // k output (8,1024,2,64)
    float* ov  = out + 7340032;            // v output

    // bf16 scratch inside the out-buffer's main region (dead until projgemm
    // overwrites it; none of it is read by projgemm):
    short* xbf   = (short*)out;
    short* wqbf  = xbf + 6291456;
    short* wkvbf = wqbf + 589824;

    char* ws = (char*)d_ws;
    short* q_ws  = (short*)(ws);                    // 12,582,912 B
    short* k_ws  = (short*)(ws + 12582912);         //  4,194,304 B (frag layout)
    short* vT_ws = (short*)(ws + 16777216);         //  4,194,304 B (frag layout)
    short* o_ws  = (short*)(ws + 20971520);         // 12,582,912 B  (32 MiB total)

    short* wpbf  = q_ws;                   // q_ws region is dead after attn_k

    cast_k     <<<dim3(3456), 256, 0, stream>>>(x, Wq, Wkv, xbf, wqbf, wkvbf);
    prep_k     <<<dim3(2048), 256, 0, stream>>>(xbf, wqbf, wkvbf, bq, bkv, dk, dv,
                                                ok, ov, q_ws, k_ws, vT_ws);
    attn_k     <<<dim3(768),  256, 0, stream>>>(q_ws, k_ws, vT_ws, o_ws);
    wpcast_k   <<<dim3(288),  256, 0, stream>>>(Wp, wpbf);
    projgemm_k <<<dim3(768),  256, 0, stream>>>(o_ws, wpbf, bpj, out);
}

// Round 13
// 209.110 us; speedup vs baseline: 1.0628x; 1.0328x over previous
//
#include <hip/hip_runtime.h>

using sh8 = __attribute__((ext_vector_type(8))) short;
using sh4 = __attribute__((ext_vector_type(4))) short;
using fx4 = __attribute__((ext_vector_type(4))) float;

#define MFMA(a,b,c)   __builtin_amdgcn_mfma_f32_16x16x32_bf16((a),(b),(c),0,0,0)

// RNE cast (epilogue scalars — accuracy-critical path)
__device__ __forceinline__ short f2bf(float f) {
    union { float f; unsigned u; } v; v.f = f;
    return (short)((v.u + 0x7fffu + ((v.u >> 16) & 1u)) >> 16);
}

// Single-instruction RNE pack of two floats to a bf16 pair (lo in low half).
__device__ __forceinline__ unsigned cvtpk(float lo, float hi) {
    unsigned r;
    asm("v_cvt_pk_bf16_f32 %0, %1, %2" : "=v"(r) : "v"(lo), "v"(hi));
    return r;
}

__device__ __forceinline__ sh8 pack8(float4 a, float4 b) {
    union { unsigned u[4]; sh8 s; } r;
    r.u[0] = cvtpk(a.x, a.y);
    r.u[1] = cvtpk(a.z, a.w);
    r.u[2] = cvtpk(b.x, b.y);
    r.u[3] = cvtpk(b.z, b.w);
    return r.s;
}

// q scale: D^-0.5 * log2(e) folded together; attn uses exp2 directly.
#define QSCALE 0.18033688011112042f

// DMA one 1KB chunk: per-lane global src, wave-uniform LDS dst (+lane*16 by HW)
#define GLOAD_LDS16(gsrc, ldst) __builtin_amdgcn_global_load_lds( \
    (const __attribute__((address_space(1))) void*)(gsrc),        \
    (__attribute__((address_space(3))) void*)(ldst), 16, 0, 0)

// ===========================================================================
// cast_k: one-shot fp32->bf16 of x (8192x768), Wq (768x768), Wkv (256x768)
// into the out-buffer's main region (dead until projgemm_k overwrites it).
// Wp is cast separately by wpcast_k into q_ws (dead after attn_k) — it must
// not alias out, which projgemm writes while reading it.
// ===========================================================================
__global__ __launch_bounds__(256) void cast_k(const float* __restrict__ x,
                                              const float* __restrict__ Wq,
                                              const float* __restrict__ Wkv,
                                              short* __restrict__ xbf,
                                              short* __restrict__ wqbf,
                                              short* __restrict__ wkvbf)
{
    const int blk = blockIdx.x, t = threadIdx.x;
    const float* src; short* dst; size_t idx8;
    if (blk < 3072)      { src = x;   dst = xbf;   idx8 = ((size_t)blk * 256 + t) * 8; }
    else if (blk < 3360) { src = Wq;  dst = wqbf;  idx8 = ((size_t)(blk - 3072) * 256 + t) * 8; }
    else                 { src = Wkv; dst = wkvbf; idx8 = ((size_t)(blk - 3360) * 256 + t) * 8; }
    float4 a = *(const float4*)(src + idx8);
    float4 b = *(const float4*)(src + idx8 + 4);
    *(sh8*)&dst[idx8] = pack8(a, b);
}

// wpcast_k: Wp (768x768 fp32) -> bf16 into q_ws region (dead after attn_k).
__global__ __launch_bounds__(256) void wpcast_k(const float* __restrict__ Wp,
                                                short* __restrict__ wpbf)
{
    const size_t idx8 = ((size_t)blockIdx.x * 256 + threadIdx.x) * 8;
    float4 a = *(const float4*)(Wp + idx8);
    float4 b = *(const float4*)(Wp + idx8 + 4);
    *(sh8*)&wpbf[idx8] = pack8(a, b);
}

// ===========================================================================
// Fragment layouts (k_ws / vT_ws, unchanged from R5):
//   k_ws : per bh, 256 chunks of 512 shorts; group (kb,g) = 4 chunks.
//   vT_ws: per bh, 256 chunks; chunk (kb*2+g)*4+dt = V B-operand permutation.
//   Chunks are lane-linear (lane*16B) => global_load_lds-compatible.
//
// GEMM staging (prep/proj): fragment-order chunk DMA.  Chunk c of a
// [16 x 32] bf16 subtile: lane l loads global row (row0 + c*16 + (l&15)),
// k-colgrp (l>>4)*8.  The MFMA fragment read is then ds_read_b128 at
// lane*16B within the chunk — linear, bank-conflict-free, no padding.
// ===========================================================================

// prep_k: merged qgemm+kvgemm (blocks 0..511, XCD-co-resident swizzle,
// ring-4 counted-vmcnt DMA pipeline) + depth_k cast (512..1535) +
// depth_v fragment gather (1536..2047).
__global__ __launch_bounds__(256) void prep_k(const short* __restrict__ xbf,
                                              const short* __restrict__ wqbf,
                                              const short* __restrict__ wkvbf,
                                              const float* __restrict__ bq,
                                              const float* __restrict__ bkv,
                                              const float* __restrict__ dk,
                                              const float* __restrict__ dv,
                                              float* __restrict__ ok,
                                              float* __restrict__ ov,
                                              short* __restrict__ q_ws,
                                              short* __restrict__ k_ws,
                                              short* __restrict__ vT_ws)
{
    __shared__ alignas(16) short L[4][16][512];   // 64 KB ring: 8 A + 8 B chunks
    const int blk = blockIdx.x;
    const int t   = threadIdx.x;

    if (blk < 512) {
        // ----- 128x128-tile bf16 GEMM (qgemm or kvgemm), DMA pipeline -----
        const int x8 = blk & 7, jj = blk >> 3;       // jj in [0,64)
        const int m  = x8 * 8 + (jj >> 3);           // [0,64)
        const int nn = jj & 7;                       // 0..5 q, 6..7 kv
        const bool isq = (nn < 6);
        const int  bm  = m * 128, bn = (isq ? nn : nn - 6) * 128;
        const short* Wmat = isq ? wqbf : wkvbf;

        const int wave = t >> 6, lane = t & 63;
        const int wm   = wave >> 1, wn = wave & 1;
        const int lhi  = lane >> 4, llo = lane & 15;
        const int l15  = lane & 15, l4 = lane >> 4;

        const short* aSrc0 = xbf  + (size_t)(bm + wave*16     + l15)*768 + l4*8;
        const short* aSrc1 = xbf  + (size_t)(bm + (wave+4)*16 + l15)*768 + l4*8;
        const short* bSrc0 = Wmat + (size_t)(bn + wave*16     + l15)*768 + l4*8;
        const short* bSrc1 = Wmat + (size_t)(bn + (wave+4)*16 + l15)*768 + l4*8;

        auto stage = [&](int s) {                     // k-step s: k0 = s*32
            const int r = s & 3;
            GLOAD_LDS16(aSrc0 + s*32, &L[r][wave][0]);
            GLOAD_LDS16(aSrc1 + s*32, &L[r][4 + wave][0]);
            GLOAD_LDS16(bSrc0 + s*32, &L[r][8 + wave][0]);
            GLOAD_LDS16(bSrc1 + s*32, &L[r][12 + wave][0]);
        };

        fx4 zero = {0.f, 0.f, 0.f, 0.f};
        fx4 acc[4][4];
        #pragma unroll
        for (int a = 0; a < 4; ++a)
            #pragma unroll
            for (int b2 = 0; b2 < 4; ++b2) acc[a][b2] = zero;

        stage(0);
        stage(1);                                     // 8 DMAs outstanding

        for (int s = 0; s < 24; ++s) {
            if (s < 22) {
                stage(s + 2);                         // outstanding 12
                asm volatile("s_waitcnt vmcnt(8)" ::: "memory");   // step s landed
            } else if (s == 22) {
                asm volatile("s_waitcnt vmcnt(4)" ::: "memory");
            } else {
                asm volatile("s_waitcnt vmcnt(0)" ::: "memory");
            }
            __builtin_amdgcn_s_barrier();
            __builtin_amdgcn_sched_barrier(0);

            const short* Lb = (const short*)&L[s & 3][0][0];
            const int lo = lane * 8;
            sh8 af[4], bf[4];
            #pragma unroll
            for (int mt = 0; mt < 4; ++mt)
                af[mt] = *(const sh8*)(Lb + (wm*4 + mt)*512 + lo);
            #pragma unroll
            for (int nt = 0; nt < 4; ++nt)
                bf[nt] = *(const sh8*)(Lb + (8 + wn*4 + nt)*512 + lo);
            #pragma unroll
            for (int mt = 0; mt < 4; ++mt)
                #pragma unroll
                for (int nt = 0; nt < 4; ++nt)
                    acc[mt][nt] = MFMA(af[mt], bf[nt], acc[mt][nt]);
        }

        if (isq) {
            #pragma unroll
            for (int nt = 0; nt < 4; ++nt) {
                const int c = bn + wn*64 + nt*16 + llo;
                const float bias = bq[c];
                const int g = c >> 7, h = (c >> 6) & 1, d = c & 63;
                #pragma unroll
                for (int mt = 0; mt < 4; ++mt) {
                    const int m0 = bm + wm*64 + mt*16 + lhi*4;
                    #pragma unroll
                    for (int r = 0; r < 4; ++r) {
                        const int mr = m0 + r;
                        const int b = mr >> 10, n = mr & 1023;
                        const float val = (acc[mt][nt][r] + bias) * QSCALE;
                        q_ws[((size_t)(b*2 + h)*6144 + n*6 + g)*64 + d] = f2bf(val);
                    }
                }
            }
        } else {
            #pragma unroll
            for (int nt = 0; nt < 4; ++nt) {
                const int c = bn + wn*64 + nt*16 + llo;     // 0..255
                const float bias = bkv[c];
                const int s = c >> 7, h = (c >> 6) & 1, d = c & 63;
                #pragma unroll
                for (int mt = 0; mt < 4; ++mt) {
                    const int m0 = bm + wm*64 + mt*16 + lhi*4;
                    const int b = m0 >> 10, n0 = m0 & 1023;
                    float vals[4];
                    #pragma unroll
                    for (int r = 0; r < 4; ++r) vals[r] = acc[mt][nt][r] + bias;
                    const int key = 1024 + n0;              // n0 % 4 == 0
                    if (s == 0) {
                        #pragma unroll
                        for (int r = 0; r < 4; ++r)
                            ok[((size_t)(b*1024 + n0 + r)*2 + h)*64 + d] = vals[r];
                        const int kb_ = key >> 6, nt_ = (key >> 4) & 3;
                        const int half = d >> 5, lhiK = (d >> 3) & 3, jK = d & 7;
                        const size_t base = (size_t)(b*2 + h)*131072
                            + (size_t)(((((kb_*4 + nt_)*2 + half)*64) + lhiK*16 + (key & 15))*8 + jK);
                        #pragma unroll
                        for (int r = 0; r < 4; ++r)
                            k_ws[base + r*8] = f2bf(vals[r]);
                    } else {
                        #pragma unroll
                        for (int r = 0; r < 4; ++r)
                            ov[((size_t)(b*1024 + n0 + r)*2 + h)*64 + d] = vals[r];
                        const int kb_ = key >> 6, g_ = (key >> 5) & 1, k5 = key & 31;
                        const int half5 = k5 >> 4, lhi5 = (k5 >> 2) & 3;   // j5 = r
                        const int dt_ = d >> 4, llov = d & 15;
                        short4 pk = make_short4(f2bf(vals[0]), f2bf(vals[1]),
                                                f2bf(vals[2]), f2bf(vals[3]));
                        const size_t base = (size_t)(b*2 + h)*131072
                            + (size_t)(((((kb_*2 + g_)*4 + dt_)*64) + lhi5*16 + llov)*8 + half5*4);
                        *(short4*)&vT_ws[base] = pk;
                    }
                }
            }
        }
    } else if (blk < 1536) {
        // ----- depth_k cast: [b][tt][h][d] fp32 -> k_ws fragment layout -----
        const size_t idx4 = ((size_t)(blk - 512) * 256 + t) * 4;
        const int b  = (int)(idx4 >> 17);
        const int rm = (int)(idx4 & 131071);
        const int tt = rm >> 7, h = (rm >> 6) & 1, d = rm & 63;   // d % 4 == 0
        float4 v = *(const float4*)(dk + idx4);
        short4 pk = make_short4(f2bf(v.x), f2bf(v.y), f2bf(v.z), f2bf(v.w));
        const int kb_ = tt >> 6, nt_ = (tt >> 4) & 3, lloK = tt & 15;
        const int half = d >> 5, lhiK = (d >> 3) & 3, jK = d & 7;  // jK in {0,4}
        const size_t addr = (size_t)(b*2 + h)*131072
            + (size_t)(((((kb_*4 + nt_)*2 + half)*64) + lhiK*16 + lloK)*8 + jK);
        *(short4*)&k_ws[addr] = pk;
    } else {
        // ----- depth_v: direct gather into V fragment layout -----
        const int unit = (blk - 1536)*4 + (t >> 6);   // 0..2047
        const int lane = t & 63, lhi = lane >> 4, llo = lane & 15;
        const int dt_ = unit & 3, g_ = (unit >> 2) & 1;
        const int kb_ = (unit >> 3) & 15, bh = unit >> 7;
        const int b = bh >> 1, h = bh & 1;
        const float* s0 = dv
            + ((size_t)((b*1024 + kb_*64 + g_*32 + lhi*4)*2 + h))*64 + dt_*16 + llo;
        union { short s[8]; sh8 v8; } o;
        #pragma unroll
        for (int jv = 0; jv < 4; ++jv) o.s[jv]     = f2bf(s0[(size_t)jv * 128]);
        #pragma unroll
        for (int jv = 0; jv < 4; ++jv) o.s[4 + jv] = f2bf(s0[(size_t)(16 + jv) * 128]);
        *(sh8*)&vT_ws[((size_t)bh*256 + (kb_*2 + g_)*4 + dt_)*512 + lane*8] = o.v8;
    }
}

// ---------------------------------------------------------------------------
// Attention: session-best config (R5/R9): 256 threads, 32 q/wave, ring-4
// counted vmcnt(4), bh-co-location swizzle, ones-MFMA denominator.
// Structural constraint (verified R7/R11/R12): MFMA-issue + VALU/trans-issue
// are additive for this instruction mix; occupancy, barrier-free, and
// SW-pipeline variants all failed to unlock co-issue.  ~60-64 us plateau.
// ---------------------------------------------------------------------------
__global__ __launch_bounds__(256) void attn_k(const short* __restrict__ q_ws,
                                              const short* __restrict__ k_ws,
                                              const short* __restrict__ vT_ws,
                                              short* __restrict__ o_ws)
{
    __shared__ alignas(16) short L[4][8][512];   // ring buf: 4 x (4 K + 4 V chunks)
    const int t    = threadIdx.x;
    const int wave = t >> 6, lane = t & 63;
    const int lhi  = lane >> 4, llo = lane & 15;
    const int blk  = blockIdx.x;
    const int x8   = blk & 7, jj = blk >> 3;       // jj in [0,96)
    const int bh   = x8 * 2 + (jj >= 48 ? 1 : 0);
    const int qt   = (jj >= 48) ? (jj - 48) : jj;  // [0,48)
    const int b    = bh >> 1, h = bh & 1;

    const short* qb = q_ws + ((size_t)bh*6144 + qt*128 + wave*32) * 64;
    sh8 qf[2][2];
    #pragma unroll
    for (int s = 0; s < 2; ++s) {
        qf[s][0] = *(const sh8*)(qb + (s*16 + llo)*64 + lhi*8);
        qf[s][1] = *(const sh8*)(qb + (s*16 + llo)*64 + lhi*8 + 32);
    }

    const short* kbase = k_ws  + (size_t)bh*131072;
    const short* vbase = vT_ws + (size_t)bh*131072;

    fx4 zero = {0.f, 0.f, 0.f, 0.f};
    fx4 oacc[2][4];
    fx4 lacc[2];
    #pragma unroll
    for (int s = 0; s < 2; ++s) {
        lacc[s] = zero;
        #pragma unroll
        for (int dt = 0; dt < 4; ++dt) oacc[s][dt] = zero;
    }

    union { unsigned u[4]; sh8 s8; } onesu;
    onesu.u[0] = onesu.u[1] = onesu.u[2] = onesu.u[3] = 0x3F803F80u;  // bf16 1.0 x8
    const sh8 ones = onesu.s8;

    auto stage = [&](int g) {
        const short* ks = kbase + ((size_t)g*4 + wave)*512 + lane*8;
        const short* vs = vbase + ((size_t)g*4 + wave)*512 + lane*8;
        GLOAD_LDS16(ks, &L[g & 3][wave][0]);
        GLOAD_LDS16(vs, &L[g & 3][4 + wave][0]);
    };

    stage(0);
    stage(1);                     // outstanding: 4 DMA ops per wave

    for (int g = 0; g < 64; ++g) {
        if (g < 62) {
            stage(g + 2);         // outstanding 6
            asm volatile("s_waitcnt vmcnt(4)" ::: "memory");   // group g landed
        } else if (g == 62) {
            asm volatile("s_waitcnt vmcnt(2)" ::: "memory");
        } else {
            asm volatile("s_waitcnt vmcnt(0)" ::: "memory");
        }
        __builtin_amdgcn_s_barrier();          // all waves' group-g DMAs visible
        __builtin_amdgcn_sched_barrier(0);     // forbid hoisting ds_reads above

        const short* Lb = (const short*)&L[g & 3][0][0];
        const int lo = lane * 8;
        sh8 K0 = *(const sh8*)(Lb + lo);
        sh8 K1 = *(const sh8*)(Lb + 512  + lo);
        sh8 K2 = *(const sh8*)(Lb + 1024 + lo);
        sh8 K3 = *(const sh8*)(Lb + 1536 + lo);
        sh8 V0 = *(const sh8*)(Lb + 2048 + lo);
        sh8 V1 = *(const sh8*)(Lb + 2560 + lo);
        sh8 V2 = *(const sh8*)(Lb + 3072 + lo);
        sh8 V3 = *(const sh8*)(Lb + 3584 + lo);

        #pragma unroll
        for (int s = 0; s < 2; ++s) {
            fx4 stA = MFMA(K0, qf[s][0], zero); stA = MFMA(K1, qf[s][1], stA);
            fx4 stB = MFMA(K2, qf[s][0], zero); stB = MFMA(K3, qf[s][1], stB);
            float pa0 = __builtin_amdgcn_exp2f(stA[0]);
            float pa1 = __builtin_amdgcn_exp2f(stA[1]);
            float pa2 = __builtin_amdgcn_exp2f(stA[2]);
            float pa3 = __builtin_amdgcn_exp2f(stA[3]);
            float pb0 = __builtin_amdgcn_exp2f(stB[0]);
            float pb1 = __builtin_amdgcn_exp2f(stB[1]);
            float pb2 = __builtin_amdgcn_exp2f(stB[2]);
            float pb3 = __builtin_amdgcn_exp2f(stB[3]);
            union { unsigned u[4]; sh8 s8; } pu;
            pu.u[0] = cvtpk(pa0, pa1);
            pu.u[1] = cvtpk(pa2, pa3);
            pu.u[2] = cvtpk(pb0, pb1);
            pu.u[3] = cvtpk(pb2, pb3);
            lacc[s]    = MFMA(pu.s8, ones, lacc[s]);
            oacc[s][0] = MFMA(pu.s8, V0, oacc[s][0]);
            oacc[s][1] = MFMA(pu.s8, V1, oacc[s][1]);
            oacc[s][2] = MFMA(pu.s8, V2, oacc[s][2]);
            oacc[s][3] = MFMA(pu.s8, V3, oacc[s][3]);
        }
    }

    #pragma unroll
    for (int s = 0; s < 2; ++s) {
        #pragma unroll
        for (int r = 0; r < 4; ++r) {
            const float iq = 1.0f / lacc[s][r];
            const int qi = qt*128 + wave*32 + s*16 + lhi*4 + r;
            const int n = qi / 6, g = qi % 6;
            short* orow = o_ws + ((size_t)(b*1024 + n))*768 + g*128 + h*64;
            #pragma unroll
            for (int dt = 0; dt < 4; ++dt)
                orow[dt*16 + llo] = f2bf(oacc[s][dt][r] * iq);
        }
    }
}

// ---------------------------------------------------------------------------
// proj GEMM: out = o(8192x768,bf16) @ Wp_bf^T + bproj -> fp32.  128x64 tiles,
// 768 blocks = 3/CU, XCD swizzle, attn-style ring-4 counted-vmcnt pipeline.
// wpbf lives in the q_ws workspace region (dead after attn) — no aliasing
// with the out buffer this kernel writes.
// ---------------------------------------------------------------------------
__global__ __launch_bounds__(256) void projgemm_k(const short* __restrict__ o_ws,
                                                  const short* __restrict__ wpbf,
                                                  const float* __restrict__ bpj,
                                                  float* __restrict__ out)
{
    __shared__ alignas(16) short L[4][12][512];   // 48 KB ring: 8 A + 4 B chunks
    const int t    = threadIdx.x;
    const int wave = t >> 6, lane = t & 63;
    const int wm   = wave >> 1, wn = wave & 1;
    const int lhi  = lane >> 4, llo = lane & 15;
    const int l15  = lane & 15, l4 = lane >> 4;
    const int x8   = blockIdx.x & 7, jj = blockIdx.x >> 3;   // jj in [0,96)
    const int bm   = (x8*8 + jj/12) * 128;
    const int bn   = (jj % 12) * 64;

    const short* aSrc0 = o_ws + (size_t)(bm + wave*16     + l15)*768 + l4*8;
    const short* aSrc1 = o_ws + (size_t)(bm + (wave+4)*16 + l15)*768 + l4*8;
    const short* bSrc  = wpbf + (size_t)(bn + wave*16     + l15)*768 + l4*8;

    auto stage = [&](int s) {
        const int r = s & 3;
        GLOAD_LDS16(aSrc0 + s*32, &L[r][wave][0]);
        GLOAD_LDS16(aSrc1 + s*32, &L[r][4 + wave][0]);
        GLOAD_LDS16(bSrc  + s*32, &L[r][8 + wave][0]);
    };

    fx4 zero = {0.f, 0.f, 0.f, 0.f};
    fx4 acc[4][2];
    #pragma unroll
    for (int i = 0; i < 4; ++i)
        #pragma unroll
        for (int j2 = 0; j2 < 2; ++j2) acc[i][j2] = zero;

    stage(0);
    stage(1);                                     // 6 DMAs outstanding

    for (int s = 0; s < 24; ++s) {
        if (s < 22) {
            stage(s + 2);                         // outstanding 9
            asm volatile("s_waitcnt vmcnt(6)" ::: "memory");   // step s landed
        } else if (s == 22) {
            asm volatile("s_waitcnt vmcnt(3)" ::: "memory");
        } else {
            asm volatile("s_waitcnt vmcnt(0)" ::: "memory");
        }
        __builtin_amdgcn_s_barrier();
        __builtin_amdgcn_sched_barrier(0);

        const short* Lb = (const short*)&L[s & 3][0][0];
        const int lo = lane * 8;
        sh8 af[4], bf[2];
        #pragma unroll
        for (int mt = 0; mt < 4; ++mt)
            af[mt] = *(const sh8*)(Lb + (wm*4 + mt)*512 + lo);
        #pragma unroll
        for (int nt = 0; nt < 2; ++nt)
            bf[nt] = *(const sh8*)(Lb + (8 + wn*2 + nt)*512 + lo);
        #pragma unroll
        for (int mt = 0; mt < 4; ++mt)
            #pragma unroll
            for (int nt = 0; nt < 2; ++nt)
                acc[mt][nt] = MFMA(af[mt], bf[nt], acc[mt][nt]);
    }

    #pragma unroll
    for (int nt = 0; nt < 2; ++nt) {
        const int c = bn + wn*32 + nt*16 + llo;
        const float bias = bpj[c];
        #pragma unroll
        for (int mt = 0; mt < 4; ++mt) {
            const int m0 = bm + wm*64 + mt*16 + lhi*4;
            #pragma unroll
            for (int r = 0; r < 4; ++r)
                out[(size_t)(m0 + r)*768 + c] = acc[mt][nt][r] + bias;
        }
    }
}

// ---------------------------------------------------------------------------
extern "C" void kernel_launch(void* const* d_in, const int* in_sizes, int n_in,
                              void* d_out, int out_size, void* d_ws, size_t ws_size,
                              hipStream_t stream)
{
    const float* x   = (const float*)d_in[0];
    const float* dk  = (const float*)d_in[1];
    const float* dv  = (const float*)d_in[2];
    const float* Wq  = (const float*)d_in[3];
    const float* bq  = (const float*)d_in[4];
    const float* Wkv = (const float*)d_in[5];
    const float* bkv = (const float*)d_in[6];
    const float* Wp  = (const float*)d_in[7];
    const float* bpj = (const float*)d_in[8];

    float* out = (float*)d_out;
    float* ok  = out + 6291456;            // k output (8,1024,2,64)
    float* ov  = out + 7340032;            // v output

    // bf16 scratch inside the out-buffer's main region (dead until projgemm
    // overwrites it; none of it is read by projgemm):
    short* xbf   = (short*)out;
    short* wqbf  = xbf + 6291456;
    short* wkvbf = wqbf + 589824;

    char* ws = (char*)d_ws;
    short* q_ws  = (short*)(ws);                    // 12,582,912 B
    short* k_ws  = (short*)(ws + 12582912);         //  4,194,304 B (frag layout)
    short* vT_ws = (short*)(ws + 16777216);         //  4,194,304 B (frag layout)
    short* o_ws  = (short*)(ws + 20971520);         // 12,582,912 B  (32 MiB total)

    short* wpbf  = q_ws;                   // q_ws region is dead after attn_k

    cast_k     <<<dim3(3456), 256, 0, stream>>>(x, Wq, Wkv, xbf, wqbf, wkvbf);
    prep_k     <<<dim3(2048), 256, 0, stream>>>(xbf, wqbf, wkvbf, bq, bkv, dk, dv,
                                                ok, ov, q_ws, k_ws, vT_ws);
    attn_k     <<<dim3(768),  256, 0, stream>>>(q_ws, k_ws, vT_ws, o_ws);
    wpcast_k   <<<dim3(288),  256, 0, stream>>>(Wp, wpbf);
    projgemm_k <<<dim3(768),  256, 0, stream>>>(o_ws, wpbf, bpj, out);
}